// Round 11
// baseline (850.332 us; speedup 1.0000x reference)
//
#include <hip/hip_runtime.h>
#include <math.h>

#define B 8
#define N 4096
#define S 1024
#define K 32
#define CIN 64
#define DIM 128
#define PTROW 68   // xyz(3) + points(64) + pad(1)
#define NWORK 504  // worker blocks; 8 FPS + 504 = 512 = 2/CU co-resident

typedef __attribute__((ext_vector_type(8))) short bfrag;
typedef __attribute__((ext_vector_type(4))) float f32x4;

#define MFMA(a, b, c) __builtin_amdgcn_mfma_f32_16x16x32_bf16((a), (b), (c), 0, 0, 0)

__device__ __forceinline__ unsigned short f2bf(float f) {
    union { float f; unsigned u; } v; v.f = f;
    unsigned r = v.u + 0x7FFFu + ((v.u >> 16) & 1u);
    return (unsigned short)(r >> 16);
}

// float max DPP step; shifted-in lanes keep old -> fmax(v,v)=v safe
#define DPPMAXF(var, CTRL) {                                                              \
    int _o = __builtin_amdgcn_update_dpp(__float_as_int(var), __float_as_int(var),        \
                                         CTRL, 0xf, 0xf, false);                          \
    var = fmaxf(var, __int_as_float(_o));                                                 \
}
#define DPPMINU(var, CTRL) {                                                              \
    unsigned _o = (unsigned)__builtin_amdgcn_update_dpp((int)(var), (int)(var),           \
                                                        CTRL, 0xf, 0xf, false);          \
    var = (_o < (var)) ? _o : (var);                                                      \
}

// ---------------- worker LDS layout (within shared smem) ----------------
#define LDS_X   0        // [32][128] bf16 swizzled: x -> P
#define LDS_A   8192     // [32][128] bf16 swizzled: feat -> q -> o
#define LDS_K   16384    // [32][128] bf16 swizzled: k
#define LDS_VT  24576    // v_t [128][56] bf16 (112B rows)
#define LDS_MISC 38912   // nidx[32] int, ctr[3] float
// FPS layout: xs 0, ys 16384, zs 32768, cent 49152 (12KB), wbuf 61440
#define SMEM_TOTAL 61952

#define LDSA_READ(off, row, colb) \
    (*(const bfrag*)(smem + (off) + ((row) << 8) + ((colb) ^ (((row) & 7) << 4))))
#define LDS_ST16(off, row, colb, val) \
    (*(unsigned short*)(smem + (off) + ((row) << 8) + ((colb) ^ (((row) & 7) << 4))) = (val))

__global__ __launch_bounds__(256) void k_fused(
    const float* __restrict__ xyz, const float* __restrict__ points,
    const float* __restrict__ Wc, const float* __restrict__ bc,
    const float* __restrict__ gamma, const float* __restrict__ beta,
    const float* __restrict__ mean, const float* __restrict__ var,
    const float* __restrict__ Wp, const float* __restrict__ bp,
    const float* __restrict__ Wq, const float* __restrict__ Wk,
    const float* __restrict__ Wv, const float* __restrict__ Wo,
    float* __restrict__ ptsT, float* nxyz, float* __restrict__ out_xyz,
    unsigned short* __restrict__ WF, float* __restrict__ biasv,
    int* flags, int* tdone, float* __restrict__ outp) {
    __shared__ __align__(16) char smem[SMEM_TOTAL];
    const int tid = threadIdx.x;
    const int blk = blockIdx.x;

    if (blk < 8) {
        // ======================= FPS producer =======================
        const int b = blk;
        const float* X = xyz + (size_t)b * 3 * N;
        float* xs = (float*)smem;
        float* ys = (float*)(smem + 16384);
        float* zs = (float*)(smem + 32768);
        float* cent = (float*)(smem + 49152);
        unsigned long long* wbuf = (unsigned long long*)(smem + 61440);  // [2][4]

        float px[16], py[16], pz[16], pd[16];
#pragma unroll
        for (int i = 0; i < 16; i++) {
            int n = tid + i * 256;
            px[i] = X[n]; py[i] = X[N + n]; pz[i] = X[2 * N + n];
            xs[n] = px[i]; ys[n] = py[i]; zs[n] = pz[i];
            pd[i] = 1e10f;
        }
        __syncthreads();
        float cx = xs[0], cy = ys[0], cz = zs[0];

        for (int t = 0; t < S; t++) {
            if (tid == 0) { cent[t * 3] = cx; cent[t * 3 + 1] = cy; cent[t * 3 + 2] = cz; }
            const bool pub = (t != 0) && ((t & 15) == 0);
            if (pub && tid < 48) {
                int row = t - 16 + tid / 3, c = tid % 3;
                __hip_atomic_store((unsigned*)&nxyz[((size_t)b * S + row) * 3 + c],
                                   __float_as_uint(cent[row * 3 + c]),
                                   __ATOMIC_RELEASE, __HIP_MEMORY_SCOPE_AGENT);
            }
            if (t == S - 1) break;

            float bv = -1.0f; int slot = 0;
#pragma unroll
            for (int i = 0; i < 16; i++) {
                float dx = px[i] - cx, dy = py[i] - cy, dz = pz[i] - cz;
                // match XLA/np: (dx*dx + dy*dy) + dz*dz, no FMA contraction
                float d = __fadd_rn(__fadd_rn(__fmul_rn(dx, dx), __fmul_rn(dy, dy)), __fmul_rn(dz, dz));
                float pn = fminf(pd[i], d);
                pd[i] = pn;
                bool gt = pn > bv;          // strict >: first slot wins within thread
                bv = gt ? pn : bv;
                slot = gt ? i : slot;
            }
            // f32 wave max (6-step DPP), then min tied index (6-step DPP)
            float m = bv;
            DPPMAXF(m, 0x111)
            DPPMAXF(m, 0x112)
            DPPMAXF(m, 0x114)
            DPPMAXF(m, 0x118)
            DPPMAXF(m, 0x142)
            DPPMAXF(m, 0x143)
            float wmax = __int_as_float(__builtin_amdgcn_readlane(__float_as_int(m), 63));
            unsigned cand = (bv == wmax) ? (unsigned)(tid + (slot << 8)) : 0xFFFFFFFFu;
            DPPMINU(cand, 0x111)
            DPPMINU(cand, 0x112)
            DPPMINU(cand, 0x114)
            DPPMINU(cand, 0x118)
            DPPMINU(cand, 0x142)
            DPPMINU(cand, 0x143)
            if ((tid & 63) == 63)
                wbuf[(t & 1) * 4 + (tid >> 6)] =
                    ((unsigned long long)__float_as_uint(wmax) << 32) | (0xFFFFFFFFu - cand);
            __syncthreads();   // drains the publish atomics + wbuf writes
            if (pub && tid == 0)
                __hip_atomic_fetch_add(&flags[b], 16, __ATOMIC_RELEASE, __HIP_MEMORY_SCOPE_AGENT);
            ulonglong2 ab = *(const ulonglong2*)&wbuf[(t & 1) * 4 + 0];
            ulonglong2 cd = *(const ulonglong2*)&wbuf[(t & 1) * 4 + 2];
            unsigned long long kA = ab.x > ab.y ? ab.x : ab.y;
            unsigned long long kB = cd.x > cd.y ? cd.x : cd.y;
            unsigned long long km = kA > kB ? kA : kB;
            int best = (int)(0xFFFFFFFFu - (unsigned)km);
            cx = xs[best]; cy = ys[best]; cz = zs[best];
        }
        __syncthreads();
        // tail publish rows 1008..1023
        if (tid < 48) {
            int row = 1008 + tid / 3, c = tid % 3;
            __hip_atomic_store((unsigned*)&nxyz[((size_t)b * S + row) * 3 + c],
                               __float_as_uint(cent[row * 3 + c]),
                               __ATOMIC_RELEASE, __HIP_MEMORY_SCOPE_AGENT);
        }
        __syncthreads();
        if (tid == 0)
            __hip_atomic_fetch_add(&flags[b], 16, __ATOMIC_RELEASE, __HIP_MEMORY_SCOPE_AGENT);
        for (int i = tid; i < S; i += 256) {
            out_xyz[b * 3 * S + i] = cent[i * 3];
            out_xyz[b * 3 * S + S + i] = cent[i * 3 + 1];
            out_xyz[b * 3 * S + 2 * S + i] = cent[i * 3 + 2];
        }
        return;
    }

    // ======================= workers =======================
    const int w = blk - 8;  // 0..NWORK-1

    // ---- phase A: transpose (+ weight swizzle + bias) ----
    {
        const int total = B * N * PTROW;
        for (int idx = w * 256 + tid; idx < total; idx += NWORK * 256) {
            int c = idx % PTROW;
            int n = (idx / PTROW) % N;
            int b = idx / (PTROW * N);
            float v = 0.0f;
            if (c < 3) v = xyz[(b * 3 + c) * N + n];
            else if (c < 67) v = points[(b * CIN + (c - 3)) * N + n];
            ptsT[idx] = v;
        }
        if (w < 19) {
            int mat, kt, base;
            if (w < 3) { mat = 0; kt = w; base = 0; }
            else { mat = 1 + (w - 3) / 4; kt = (w - 3) % 4; base = 12288 + (mat - 1) * 16384; }
            const float* W = (mat == 1) ? Wq : (mat == 2) ? Wk : (mat == 3) ? Wv : Wo;
            const int lane = tid & 63;
#pragma unroll
            for (int g2 = 0; g2 < 2; g2++) {
                int gnt = (tid >> 6) * 2 + g2;
                int n = gnt * 16 + (lane & 15);
                int k0 = kt * 32 + (lane >> 4) * 8;
                unsigned short* dst = WF + base + (size_t)((kt * 8 + gnt) * 64 + lane) * 8;
                float a = (mat == 0) ? (gamma[n] / sqrtf(var[n] + 1e-5f)) : 0.0f;
#pragma unroll
                for (int i = 0; i < 8; i++) {
                    int k = k0 + i;
                    float v;
                    if (mat == 0) v = (k < 67) ? Wc[n * 67 + k] * a : (k < 70) ? Wp[(k - 67) * 128 + n] : 0.0f;
                    else v = W[k * 128 + n];
                    dst[i] = f2bf(v);
                }
            }
        }
        if (w == 19 && tid < DIM) {
            float a = gamma[tid] / sqrtf(var[tid] + 1e-5f);
            biasv[tid] = bc[tid] * a + beta[tid] - mean[tid] * a + bp[tid];
        }
    }
    __threadfence();
    __syncthreads();
    if (tid == 0) {
        __hip_atomic_fetch_add(tdone, 1, __ATOMIC_RELEASE, __HIP_MEMORY_SCOPE_AGENT);
        while (__hip_atomic_load(tdone, __ATOMIC_ACQUIRE, __HIP_MEMORY_SCOPE_AGENT) < NWORK)
            __builtin_amdgcn_s_sleep(2);
    }
    __syncthreads();

    // ---- phase B: groups (s-major so earliest centroids first) ----
    const int wv = tid >> 6, l = tid & 63;
    const int lane16 = l & 15, lquad = l >> 4;
    const int ncol = wv * 32;
    int* nidx = (int*)(smem + LDS_MISC);
    float* ctr = (float*)(smem + LDS_MISC + 128);

    for (int g = w; g < B * S; g += NWORK) {
        const int s = g >> 3, b = g & 7;
        if (tid == 0) {
            while (__hip_atomic_load(&flags[b], __ATOMIC_ACQUIRE, __HIP_MEMORY_SCOPE_AGENT) <= s)
                __builtin_amdgcn_s_sleep(2);
        }
        __syncthreads();   // flag acquired; also protects LDS reuse from previous group

        // ball query (wave 0) + zero-fill (all threads)
        if (tid < 64) {
            float cx = __uint_as_float(__hip_atomic_load((unsigned*)&nxyz[((size_t)b * S + s) * 3 + 0],
                                                         __ATOMIC_RELAXED, __HIP_MEMORY_SCOPE_AGENT));
            float cy = __uint_as_float(__hip_atomic_load((unsigned*)&nxyz[((size_t)b * S + s) * 3 + 1],
                                                         __ATOMIC_RELAXED, __HIP_MEMORY_SCOPE_AGENT));
            float cz = __uint_as_float(__hip_atomic_load((unsigned*)&nxyz[((size_t)b * S + s) * 3 + 2],
                                                         __ATOMIC_RELAXED, __HIP_MEMORY_SCOPE_AGENT));
            if (tid == 0) { ctr[0] = cx; ctr[1] = cy; ctr[2] = cz; }
            const float* X = xyz + (size_t)b * 3 * N;
            int cnt = 0, first = -1;
            for (int base = 0; base < N && cnt < K; base += 64) {
                int n = base + tid;
                float dx = cx - X[n], dy = cy - X[N + n], dz = cz - X[2 * N + n];
                float d = __fadd_rn(__fadd_rn(__fmul_rn(dx, dx), __fmul_rn(dy, dy)), __fmul_rn(dz, dz));
                bool in = (d <= 0.04f);
                unsigned long long mm = __ballot(in);
                int pre = __popcll(mm & ((1ull << tid) - 1ull));
                if (in && cnt + pre < K) nidx[cnt + pre] = n;
                if (first < 0 && mm) first = base + (int)__ffsll((unsigned long long)mm) - 1;
                cnt += __popcll(mm);
            }
            if (cnt < K) {
                for (int i = cnt + tid; i < K; i += 64) nidx[i] = first;
            }
        }
        for (int i = tid; i < 32 * 32; i += 256) {
            int p = i >> 5, c = 64 + (i & 31);
            LDS_ST16(LDS_A, p, c * 2, (unsigned short)0);
        }
        __syncthreads();

        // gather feat
        {
            const int p = tid >> 3, j = tid & 7;
            const float* src = ptsT + (size_t)(b * N + nidx[p]) * PTROW;
            float c0 = ctr[0], c1 = ctr[1], c2 = ctr[2];
            for (int c = j; c < 70; c += 8) {
                float v;
                if (c < 3) v = src[c] - (c == 0 ? c0 : c == 1 ? c1 : c2);
                else if (c < 67) v = src[c];
                else v = src[c - 67];
                LDS_ST16(LDS_A, p, c * 2, f2bf(v));
            }
        }
        __syncthreads();

        // GEMM1: x = feat @ Wall + bias
        f32x4 accx[2][2];
        {
            float bv0 = biasv[ncol + lane16], bv1 = biasv[ncol + 16 + lane16];
            accx[0][0] = f32x4{bv0, bv0, bv0, bv0}; accx[1][0] = accx[0][0];
            accx[0][1] = f32x4{bv1, bv1, bv1, bv1}; accx[1][1] = accx[0][1];
            const bfrag* WallF = (const bfrag*)WF;
#pragma unroll
            for (int kt = 0; kt < 3; kt++) {
                bfrag a0 = LDSA_READ(LDS_A, lane16, kt * 64 + lquad * 16);
                bfrag a1 = LDSA_READ(LDS_A, 16 + lane16, kt * 64 + lquad * 16);
                bfrag b0 = WallF[(kt * 8 + wv * 2 + 0) * 64 + l];
                bfrag b1 = WallF[(kt * 8 + wv * 2 + 1) * 64 + l];
                accx[0][0] = MFMA(a0, b0, accx[0][0]);
                accx[0][1] = MFMA(a0, b1, accx[0][1]);
                accx[1][0] = MFMA(a1, b0, accx[1][0]);
                accx[1][1] = MFMA(a1, b1, accx[1][1]);
            }
#pragma unroll
            for (int mt = 0; mt < 2; mt++)
#pragma unroll
                for (int nt = 0; nt < 2; nt++)
#pragma unroll
                    for (int r = 0; r < 4; r++)
                        LDS_ST16(LDS_X, mt * 16 + lquad * 4 + r, (ncol + nt * 16 + lane16) * 2,
                                 f2bf(accx[mt][nt][r]));
        }
        __syncthreads();

        // GEMM2-4: q,k,v
        {
            const bfrag* WQF = (const bfrag*)(WF + 12288);
            const bfrag* WKF = (const bfrag*)(WF + 28672);
            const bfrag* WVF = (const bfrag*)(WF + 45056);
#pragma unroll
            for (int m = 0; m < 3; m++) {
                const bfrag* BW = (m == 0) ? WQF : (m == 1) ? WKF : WVF;
                f32x4 acc[2][2] = {};
#pragma unroll
                for (int kt = 0; kt < 4; kt++) {
                    bfrag a0 = LDSA_READ(LDS_X, lane16, kt * 64 + lquad * 16);
                    bfrag a1 = LDSA_READ(LDS_X, 16 + lane16, kt * 64 + lquad * 16);
                    bfrag b0 = BW[(kt * 8 + wv * 2 + 0) * 64 + l];
                    bfrag b1 = BW[(kt * 8 + wv * 2 + 1) * 64 + l];
                    acc[0][0] = MFMA(a0, b0, acc[0][0]);
                    acc[0][1] = MFMA(a0, b1, acc[0][1]);
                    acc[1][0] = MFMA(a1, b0, acc[1][0]);
                    acc[1][1] = MFMA(a1, b1, acc[1][1]);
                }
                if (m < 2) {
                    int dst = (m == 0) ? LDS_A : LDS_K;
#pragma unroll
                    for (int mt = 0; mt < 2; mt++)
#pragma unroll
                        for (int nt = 0; nt < 2; nt++)
#pragma unroll
                            for (int r = 0; r < 4; r++)
                                LDS_ST16(dst, mt * 16 + lquad * 4 + r, (ncol + nt * 16 + lane16) * 2,
                                         f2bf(acc[mt][nt][r]));
                } else {
#pragma unroll
                    for (int mt = 0; mt < 2; mt++)
#pragma unroll
                        for (int nt = 0; nt < 2; nt++)
#pragma unroll
                            for (int r = 0; r < 4; r++) {
                                int d = ncol + nt * 16 + lane16;
                                int j = mt * 16 + lquad * 4 + r;
                                *(unsigned short*)(smem + LDS_VT + d * 112 + j * 2) = f2bf(acc[mt][nt][r]);
                            }
                }
            }
        }
        __syncthreads();

        // scores + softmax + PV
        {
            const int h = wv;
            const int hb = h * 64;
            bfrag aq0 = LDSA_READ(LDS_A, lane16, hb + lquad * 16);
            bfrag aq1 = LDSA_READ(LDS_A, 16 + lane16, hb + lquad * 16);
            bfrag bk0 = LDSA_READ(LDS_K, lane16, hb + lquad * 16);
            bfrag bk1 = LDSA_READ(LDS_K, 16 + lane16, hb + lquad * 16);
            f32x4 sc[2][2] = {};
            sc[0][0] = MFMA(aq0, bk0, sc[0][0]);
            sc[0][1] = MFMA(aq0, bk1, sc[0][1]);
            sc[1][0] = MFMA(aq1, bk0, sc[1][0]);
            sc[1][1] = MFMA(aq1, bk1, sc[1][1]);

            const float scale = 0.17677669529663687f;
            float p_[2][2][4];
            float mx[2][4], sm[2][4];
#pragma unroll
            for (int mt = 0; mt < 2; mt++)
#pragma unroll
                for (int r = 0; r < 4; r++) {
                    p_[mt][0][r] = sc[mt][0][r] * scale;
                    p_[mt][1][r] = sc[mt][1][r] * scale;
                    mx[mt][r] = fmaxf(p_[mt][0][r], p_[mt][1][r]);
                }
#pragma unroll
            for (int d = 1; d < 16; d <<= 1)
#pragma unroll
                for (int mt = 0; mt < 2; mt++)
#pragma unroll
                    for (int r = 0; r < 4; r++)
                        mx[mt][r] = fmaxf(mx[mt][r], __shfl_xor(mx[mt][r], d));
#pragma unroll
            for (int mt = 0; mt < 2; mt++)
#pragma unroll
                for (int r = 0; r < 4; r++) {
                    float e0 = __expf(p_[mt][0][r] - mx[mt][r]);
                    float e1 = __expf(p_[mt][1][r] - mx[mt][r]);
                    p_[mt][0][r] = e0; p_[mt][1][r] = e1;
                    sm[mt][r] = e0 + e1;
                }
#pragma unroll
            for (int d = 1; d < 16; d <<= 1)
#pragma unroll
                for (int mt = 0; mt < 2; mt++)
#pragma unroll
                    for (int r = 0; r < 4; r++)
                        sm[mt][r] += __shfl_xor(sm[mt][r], d);
#pragma unroll
            for (int mt = 0; mt < 2; mt++)
#pragma unroll
                for (int r = 0; r < 4; r++) {
                    float inv = 1.0f / sm[mt][r];
                    int row = mt * 16 + lquad * 4 + r;
                    LDS_ST16(LDS_X, row, (h * 32 + lane16) * 2, f2bf(p_[mt][0][r] * inv));
                    LDS_ST16(LDS_X, row, (h * 32 + 16 + lane16) * 2, f2bf(p_[mt][1][r] * inv));
                }

            f32x4 oacc[2][2] = {};
            bfrag ap0 = LDSA_READ(LDS_X, lane16, hb + lquad * 16);
            bfrag ap1 = LDSA_READ(LDS_X, 16 + lane16, hb + lquad * 16);
            bfrag bv0 = *(const bfrag*)(smem + LDS_VT + (h * 32 + lane16) * 112 + lquad * 16);
            bfrag bv1 = *(const bfrag*)(smem + LDS_VT + (h * 32 + 16 + lane16) * 112 + lquad * 16);
            oacc[0][0] = MFMA(ap0, bv0, oacc[0][0]);
            oacc[0][1] = MFMA(ap0, bv1, oacc[0][1]);
            oacc[1][0] = MFMA(ap1, bv0, oacc[1][0]);
            oacc[1][1] = MFMA(ap1, bv1, oacc[1][1]);
#pragma unroll
            for (int mt = 0; mt < 2; mt++)
#pragma unroll
                for (int nt = 0; nt < 2; nt++)
#pragma unroll
                    for (int r = 0; r < 4; r++)
                        LDS_ST16(LDS_A, mt * 16 + lquad * 4 + r, (h * 32 + nt * 16 + lane16) * 2,
                                 f2bf(oacc[mt][nt][r]));
        }
        __syncthreads();

        // GEMM7: out = x + o @ Wo ; maxpool
        {
            const bfrag* WOF = (const bfrag*)(WF + 61440);
            f32x4 acc[2][2];
#pragma unroll
            for (int mt = 0; mt < 2; mt++)
#pragma unroll
                for (int nt = 0; nt < 2; nt++) acc[mt][nt] = accx[mt][nt];
#pragma unroll
            for (int kt = 0; kt < 4; kt++) {
                bfrag a0 = LDSA_READ(LDS_A, lane16, kt * 64 + lquad * 16);
                bfrag a1 = LDSA_READ(LDS_A, 16 + lane16, kt * 64 + lquad * 16);
                bfrag b0 = WOF[(kt * 8 + wv * 2 + 0) * 64 + l];
                bfrag b1 = WOF[(kt * 8 + wv * 2 + 1) * 64 + l];
                acc[0][0] = MFMA(a0, b0, acc[0][0]);
                acc[0][1] = MFMA(a0, b1, acc[0][1]);
                acc[1][0] = MFMA(a1, b0, acc[1][0]);
                acc[1][1] = MFMA(a1, b1, acc[1][1]);
            }
            float mnt[2];
#pragma unroll
            for (int nt = 0; nt < 2; nt++) {
                float m = acc[0][nt][0];
#pragma unroll
                for (int r = 1; r < 4; r++) m = fmaxf(m, acc[0][nt][r]);
#pragma unroll
                for (int r = 0; r < 4; r++) m = fmaxf(m, acc[1][nt][r]);
                m = fmaxf(m, __shfl_xor(m, 16));
                m = fmaxf(m, __shfl_xor(m, 32));
                mnt[nt] = m;
            }
            if (lquad == 0) {
#pragma unroll
                for (int nt = 0; nt < 2; nt++) {
                    int d = ncol + nt * 16 + lane16;
                    outp[((size_t)b * DIM + d) * S + s] = mnt[nt];
                }
            }
        }
    }
}

extern "C" void kernel_launch(void* const* d_in, const int* in_sizes, int n_in,
                              void* d_out, int out_size, void* d_ws, size_t ws_size,
                              hipStream_t stream) {
    const float* xyz = (const float*)d_in[0];
    const float* points = (const float*)d_in[1];
    const float* Wc = (const float*)d_in[2];
    const float* bc = (const float*)d_in[3];
    const float* gamma = (const float*)d_in[4];
    const float* beta = (const float*)d_in[5];
    const float* mean = (const float*)d_in[6];
    const float* var = (const float*)d_in[7];
    const float* Wq = (const float*)d_in[8];
    const float* Wk = (const float*)d_in[9];
    const float* Wv = (const float*)d_in[10];
    const float* Wo = (const float*)d_in[11];
    const float* Wp = (const float*)d_in[12];
    const float* bp = (const float*)d_in[13];

    float* out_xyz = (float*)d_out;
    float* out_pts = out_xyz + B * 3 * S;

    char* ws = (char*)d_ws;
    float* ptsT = (float*)ws;
    size_t off = (size_t)B * N * PTROW * 4;
    float* nxyz = (float*)(ws + off); off += (size_t)B * S * 3 * 4;
    unsigned short* WF = (unsigned short*)(ws + off); off += 77824 * 2;
    float* biasv = (float*)(ws + off); off += DIM * 4;
    off = (off + 255) & ~(size_t)255;
    int* flags = (int*)(ws + off);           // flags[0..7], tdone at +8
    int* tdone = flags + 8;

    hipMemsetAsync(flags, 0, 64, stream);
    k_fused<<<8 + NWORK, 256, 0, stream>>>(
        xyz, points, Wc, bc, gamma, beta, mean, var, Wp, bp, Wq, Wk, Wv, Wo,
        ptsT, nxyz, out_xyz, WF, biasv, flags, tdone, out_pts);
}

// Round 12
// 766.862 us; speedup vs baseline: 1.1088x; 1.1088x over previous
//
#include <hip/hip_runtime.h>
#include <math.h>

#define B 8
#define N 4096
#define S 1024
#define K 32
#define CIN 64
#define DIM 128
#define PTROW 68   // xyz(3) + points(64) + pad(1)
#define NWORK 248  // 8 FPS + 248 workers = 256 blocks = 1/CU (FPS gets its own CU)

typedef __attribute__((ext_vector_type(8))) short bfrag;
typedef __attribute__((ext_vector_type(4))) float f32x4;

#define MFMA(a, b, c) __builtin_amdgcn_mfma_f32_16x16x32_bf16((a), (b), (c), 0, 0, 0)

__device__ __forceinline__ unsigned short f2bf(float f) {
    union { float f; unsigned u; } v; v.f = f;
    unsigned r = v.u + 0x7FFFu + ((v.u >> 16) & 1u);
    return (unsigned short)(r >> 16);
}

// float max DPP step; shifted-in lanes keep old -> fmax(v,v)=v safe
#define DPPMAXF(var, CTRL) {                                                              \
    int _o = __builtin_amdgcn_update_dpp(__float_as_int(var), __float_as_int(var),        \
                                         CTRL, 0xf, 0xf, false);                          \
    var = fmaxf(var, __int_as_float(_o));                                                 \
}
#define DPPMINU(var, CTRL) {                                                              \
    unsigned _o = (unsigned)__builtin_amdgcn_update_dpp((int)(var), (int)(var),           \
                                                        CTRL, 0xf, 0xf, false);          \
    var = (_o < (var)) ? _o : (var);                                                      \
}

// ---------------- worker LDS layout (within shared smem) ----------------
#define LDS_X   0        // [32][128] bf16 swizzled: x -> P
#define LDS_A   8192     // [32][128] bf16 swizzled: feat -> q -> o
#define LDS_K   16384    // [32][128] bf16 swizzled: k
#define LDS_VT  24576    // v_t [128][56] bf16 (112B rows)
#define LDS_MISC 38912   // nidx[32] int, ctr[3] float
// FPS layout: xs 0, ys 16384, zs 32768, cent 49152 (12KB), wbuf 61440
#define SMEM_TOTAL 61952

#define LDSA_READ(off, row, colb) \
    (*(const bfrag*)(smem + (off) + ((row) << 8) + ((colb) ^ (((row) & 7) << 4))))
#define LDS_ST16(off, row, colb, val) \
    (*(unsigned short*)(smem + (off) + ((row) << 8) + ((colb) ^ (((row) & 7) << 4))) = (val))

__global__ __launch_bounds__(256) void k_fused(
    const float* __restrict__ xyz, const float* __restrict__ points,
    const float* __restrict__ Wc, const float* __restrict__ bc,
    const float* __restrict__ gamma, const float* __restrict__ beta,
    const float* __restrict__ mean, const float* __restrict__ var,
    const float* __restrict__ Wp, const float* __restrict__ bp,
    const float* __restrict__ Wq, const float* __restrict__ Wk,
    const float* __restrict__ Wv, const float* __restrict__ Wo,
    float* __restrict__ ptsT, float* nxyz, float* __restrict__ out_xyz,
    unsigned short* __restrict__ WF, float* __restrict__ biasv,
    int* flags, int* tdone, float* __restrict__ outp) {
    __shared__ __align__(16) char smem[SMEM_TOTAL];
    const int tid = threadIdx.x;
    const int blk = blockIdx.x;

    if (blk < 8) {
        // ======================= FPS producer =======================
        const int b = blk;
        const float* X = xyz + (size_t)b * 3 * N;
        float* xs = (float*)smem;
        float* ys = (float*)(smem + 16384);
        float* zs = (float*)(smem + 32768);
        float* cent = (float*)(smem + 49152);
        unsigned long long* wbuf = (unsigned long long*)(smem + 61440);  // [2][4]

        float px[16], py[16], pz[16], pd[16];
#pragma unroll
        for (int i = 0; i < 16; i++) {
            int n = tid + i * 256;
            px[i] = X[n]; py[i] = X[N + n]; pz[i] = X[2 * N + n];
            xs[n] = px[i]; ys[n] = py[i]; zs[n] = pz[i];
            pd[i] = 1e10f;
        }
        __syncthreads();
        float cx = xs[0], cy = ys[0], cz = zs[0];

        for (int t = 0; t < S; t++) {
            if (tid == 0) { cent[t * 3] = cx; cent[t * 3 + 1] = cy; cent[t * 3 + 2] = cz; }
            const bool pub = (t != 0) && ((t & 15) == 0);
            if (pub && tid < 48) {
                int row = t - 16 + tid / 3, c = tid % 3;
                __hip_atomic_store((unsigned*)&nxyz[((size_t)b * S + row) * 3 + c],
                                   __float_as_uint(cent[row * 3 + c]),
                                   __ATOMIC_RELEASE, __HIP_MEMORY_SCOPE_AGENT);
            }
            if (t == S - 1) break;

            float bv = -1.0f; int slot = 0;
#pragma unroll
            for (int i = 0; i < 16; i++) {
                float dx = px[i] - cx, dy = py[i] - cy, dz = pz[i] - cz;
                // match XLA/np: (dx*dx + dy*dy) + dz*dz, no FMA contraction
                float d = __fadd_rn(__fadd_rn(__fmul_rn(dx, dx), __fmul_rn(dy, dy)), __fmul_rn(dz, dz));
                float pn = fminf(pd[i], d);
                pd[i] = pn;
                bool gt = pn > bv;          // strict >: first slot wins within thread
                bv = gt ? pn : bv;
                slot = gt ? i : slot;
            }
            // f32 wave max (6-step DPP), then min tied index (6-step DPP)
            float m = bv;
            DPPMAXF(m, 0x111)
            DPPMAXF(m, 0x112)
            DPPMAXF(m, 0x114)
            DPPMAXF(m, 0x118)
            DPPMAXF(m, 0x142)
            DPPMAXF(m, 0x143)
            float wmax = __int_as_float(__builtin_amdgcn_readlane(__float_as_int(m), 63));
            unsigned cand = (bv == wmax) ? (unsigned)(tid + (slot << 8)) : 0xFFFFFFFFu;
            DPPMINU(cand, 0x111)
            DPPMINU(cand, 0x112)
            DPPMINU(cand, 0x114)
            DPPMINU(cand, 0x118)
            DPPMINU(cand, 0x142)
            DPPMINU(cand, 0x143)
            if ((tid & 63) == 63)
                wbuf[(t & 1) * 4 + (tid >> 6)] =
                    ((unsigned long long)__float_as_uint(wmax) << 32) | (0xFFFFFFFFu - cand);
            __syncthreads();   // drains the publish atomics + wbuf writes
            if (pub && tid == 0)
                __hip_atomic_fetch_add(&flags[b * 16], 16, __ATOMIC_RELEASE, __HIP_MEMORY_SCOPE_AGENT);
            ulonglong2 ab = *(const ulonglong2*)&wbuf[(t & 1) * 4 + 0];
            ulonglong2 cd = *(const ulonglong2*)&wbuf[(t & 1) * 4 + 2];
            unsigned long long kA = ab.x > ab.y ? ab.x : ab.y;
            unsigned long long kB = cd.x > cd.y ? cd.x : cd.y;
            unsigned long long km = kA > kB ? kA : kB;
            int best = (int)(0xFFFFFFFFu - (unsigned)km);
            cx = xs[best]; cy = ys[best]; cz = zs[best];
        }
        __syncthreads();
        // tail publish rows 1008..1023
        if (tid < 48) {
            int row = 1008 + tid / 3, c = tid % 3;
            __hip_atomic_store((unsigned*)&nxyz[((size_t)b * S + row) * 3 + c],
                               __float_as_uint(cent[row * 3 + c]),
                               __ATOMIC_RELEASE, __HIP_MEMORY_SCOPE_AGENT);
        }
        __syncthreads();
        if (tid == 0)
            __hip_atomic_fetch_add(&flags[b * 16], 16, __ATOMIC_RELEASE, __HIP_MEMORY_SCOPE_AGENT);
        for (int i = tid; i < S; i += 256) {
            out_xyz[b * 3 * S + i] = cent[i * 3];
            out_xyz[b * 3 * S + S + i] = cent[i * 3 + 1];
            out_xyz[b * 3 * S + 2 * S + i] = cent[i * 3 + 2];
        }
        return;
    }

    // ======================= workers =======================
    const int w = blk - 8;  // 0..NWORK-1

    // ---- phase A: transpose (+ weight swizzle + bias) ----
    {
        const int total = B * N * PTROW;
        for (int idx = w * 256 + tid; idx < total; idx += NWORK * 256) {
            int c = idx % PTROW;
            int n = (idx / PTROW) % N;
            int b = idx / (PTROW * N);
            float v = 0.0f;
            if (c < 3) v = xyz[(b * 3 + c) * N + n];
            else if (c < 67) v = points[(b * CIN + (c - 3)) * N + n];
            ptsT[idx] = v;
        }
        if (w < 19) {
            int mat, kt, base;
            if (w < 3) { mat = 0; kt = w; base = 0; }
            else { mat = 1 + (w - 3) / 4; kt = (w - 3) % 4; base = 12288 + (mat - 1) * 16384; }
            const float* W = (mat == 1) ? Wq : (mat == 2) ? Wk : (mat == 3) ? Wv : Wo;
            const int lane = tid & 63;
#pragma unroll
            for (int g2 = 0; g2 < 2; g2++) {
                int gnt = (tid >> 6) * 2 + g2;
                int n = gnt * 16 + (lane & 15);
                int k0 = kt * 32 + (lane >> 4) * 8;
                unsigned short* dst = WF + base + (size_t)((kt * 8 + gnt) * 64 + lane) * 8;
                float a = (mat == 0) ? (gamma[n] / sqrtf(var[n] + 1e-5f)) : 0.0f;
#pragma unroll
                for (int i = 0; i < 8; i++) {
                    int k = k0 + i;
                    float v;
                    if (mat == 0) v = (k < 67) ? Wc[n * 67 + k] * a : (k < 70) ? Wp[(k - 67) * 128 + n] : 0.0f;
                    else v = W[k * 128 + n];
                    dst[i] = f2bf(v);
                }
            }
        }
        if (w == 19 && tid < DIM) {
            float a = gamma[tid] / sqrtf(var[tid] + 1e-5f);
            biasv[tid] = bc[tid] * a + beta[tid] - mean[tid] * a + bp[tid];
        }
    }
    __threadfence();
    __syncthreads();
    if (tid == 0) {
        __hip_atomic_fetch_add(tdone, 1, __ATOMIC_RELEASE, __HIP_MEMORY_SCOPE_AGENT);
        while (__hip_atomic_load(tdone, __ATOMIC_ACQUIRE, __HIP_MEMORY_SCOPE_AGENT) < NWORK)
            __builtin_amdgcn_s_sleep(4);
    }
    __syncthreads();

    // ---- phase B: groups (s-major so earliest centroids first) ----
    const int wv = tid >> 6, l = tid & 63;
    const int lane16 = l & 15, lquad = l >> 4;
    const int ncol = wv * 32;
    int* nidx = (int*)(smem + LDS_MISC);
    float* ctr = (float*)(smem + LDS_MISC + 128);

    for (int g = w; g < B * S; g += NWORK) {
        const int s = g >> 3, b = g & 7;
        if (tid == 0) {
            while (__hip_atomic_load(&flags[b * 16], __ATOMIC_ACQUIRE, __HIP_MEMORY_SCOPE_AGENT) <= s)
                __builtin_amdgcn_s_sleep(4);
        }
        __syncthreads();   // flag acquired; also protects LDS reuse from previous group

        // ball query (wave 0) + zero-fill (all threads)
        if (tid < 64) {
            float cx = __uint_as_float(__hip_atomic_load((unsigned*)&nxyz[((size_t)b * S + s) * 3 + 0],
                                                         __ATOMIC_RELAXED, __HIP_MEMORY_SCOPE_AGENT));
            float cy = __uint_as_float(__hip_atomic_load((unsigned*)&nxyz[((size_t)b * S + s) * 3 + 1],
                                                         __ATOMIC_RELAXED, __HIP_MEMORY_SCOPE_AGENT));
            float cz = __uint_as_float(__hip_atomic_load((unsigned*)&nxyz[((size_t)b * S + s) * 3 + 2],
                                                         __ATOMIC_RELAXED, __HIP_MEMORY_SCOPE_AGENT));
            if (tid == 0) { ctr[0] = cx; ctr[1] = cy; ctr[2] = cz; }
            const float* X = xyz + (size_t)b * 3 * N;
            int cnt = 0, first = -1;
            for (int base = 0; base < N && cnt < K; base += 64) {
                int n = base + tid;
                float dx = cx - X[n], dy = cy - X[N + n], dz = cz - X[2 * N + n];
                float d = __fadd_rn(__fadd_rn(__fmul_rn(dx, dx), __fmul_rn(dy, dy)), __fmul_rn(dz, dz));
                bool in = (d <= 0.04f);
                unsigned long long mm = __ballot(in);
                int pre = __popcll(mm & ((1ull << tid) - 1ull));
                if (in && cnt + pre < K) nidx[cnt + pre] = n;
                if (first < 0 && mm) first = base + (int)__ffsll((unsigned long long)mm) - 1;
                cnt += __popcll(mm);
            }
            if (cnt < K) {
                for (int i = cnt + tid; i < K; i += 64) nidx[i] = first;
            }
        }
        for (int i = tid; i < 32 * 32; i += 256) {
            int p = i >> 5, c = 64 + (i & 31);
            LDS_ST16(LDS_A, p, c * 2, (unsigned short)0);
        }
        __syncthreads();

        // gather feat
        {
            const int p = tid >> 3, j = tid & 7;
            const float* src = ptsT + (size_t)(b * N + nidx[p]) * PTROW;
            float c0 = ctr[0], c1 = ctr[1], c2 = ctr[2];
            for (int c = j; c < 70; c += 8) {
                float v;
                if (c < 3) v = src[c] - (c == 0 ? c0 : c == 1 ? c1 : c2);
                else if (c < 67) v = src[c];
                else v = src[c - 67];
                LDS_ST16(LDS_A, p, c * 2, f2bf(v));
            }
        }
        __syncthreads();

        // GEMM1: x = feat @ Wall + bias
        f32x4 accx[2][2];
        {
            float bv0 = biasv[ncol + lane16], bv1 = biasv[ncol + 16 + lane16];
            accx[0][0] = f32x4{bv0, bv0, bv0, bv0}; accx[1][0] = accx[0][0];
            accx[0][1] = f32x4{bv1, bv1, bv1, bv1}; accx[1][1] = accx[0][1];
            const bfrag* WallF = (const bfrag*)WF;
#pragma unroll
            for (int kt = 0; kt < 3; kt++) {
                bfrag a0 = LDSA_READ(LDS_A, lane16, kt * 64 + lquad * 16);
                bfrag a1 = LDSA_READ(LDS_A, 16 + lane16, kt * 64 + lquad * 16);
                bfrag b0 = WallF[(kt * 8 + wv * 2 + 0) * 64 + l];
                bfrag b1 = WallF[(kt * 8 + wv * 2 + 1) * 64 + l];
                accx[0][0] = MFMA(a0, b0, accx[0][0]);
                accx[0][1] = MFMA(a0, b1, accx[0][1]);
                accx[1][0] = MFMA(a1, b0, accx[1][0]);
                accx[1][1] = MFMA(a1, b1, accx[1][1]);
            }
#pragma unroll
            for (int mt = 0; mt < 2; mt++)
#pragma unroll
                for (int nt = 0; nt < 2; nt++)
#pragma unroll
                    for (int r = 0; r < 4; r++)
                        LDS_ST16(LDS_X, mt * 16 + lquad * 4 + r, (ncol + nt * 16 + lane16) * 2,
                                 f2bf(accx[mt][nt][r]));
        }
        __syncthreads();

        // GEMM2-4: q,k,v
        {
            const bfrag* WQF = (const bfrag*)(WF + 12288);
            const bfrag* WKF = (const bfrag*)(WF + 28672);
            const bfrag* WVF = (const bfrag*)(WF + 45056);
#pragma unroll
            for (int m = 0; m < 3; m++) {
                const bfrag* BW = (m == 0) ? WQF : (m == 1) ? WKF : WVF;
                f32x4 acc[2][2] = {};
#pragma unroll
                for (int kt = 0; kt < 4; kt++) {
                    bfrag a0 = LDSA_READ(LDS_X, lane16, kt * 64 + lquad * 16);
                    bfrag a1 = LDSA_READ(LDS_X, 16 + lane16, kt * 64 + lquad * 16);
                    bfrag b0 = BW[(kt * 8 + wv * 2 + 0) * 64 + l];
                    bfrag b1 = BW[(kt * 8 + wv * 2 + 1) * 64 + l];
                    acc[0][0] = MFMA(a0, b0, acc[0][0]);
                    acc[0][1] = MFMA(a0, b1, acc[0][1]);
                    acc[1][0] = MFMA(a1, b0, acc[1][0]);
                    acc[1][1] = MFMA(a1, b1, acc[1][1]);
                }
                if (m < 2) {
                    int dst = (m == 0) ? LDS_A : LDS_K;
#pragma unroll
                    for (int mt = 0; mt < 2; mt++)
#pragma unroll
                        for (int nt = 0; nt < 2; nt++)
#pragma unroll
                            for (int r = 0; r < 4; r++)
                                LDS_ST16(dst, mt * 16 + lquad * 4 + r, (ncol + nt * 16 + lane16) * 2,
                                         f2bf(acc[mt][nt][r]));
                } else {
#pragma unroll
                    for (int mt = 0; mt < 2; mt++)
#pragma unroll
                        for (int nt = 0; nt < 2; nt++)
#pragma unroll
                            for (int r = 0; r < 4; r++) {
                                int d = ncol + nt * 16 + lane16;
                                int j = mt * 16 + lquad * 4 + r;
                                *(unsigned short*)(smem + LDS_VT + d * 112 + j * 2) = f2bf(acc[mt][nt][r]);
                            }
                }
            }
        }
        __syncthreads();

        // scores + softmax + PV
        {
            const int h = wv;
            const int hb = h * 64;
            bfrag aq0 = LDSA_READ(LDS_A, lane16, hb + lquad * 16);
            bfrag aq1 = LDSA_READ(LDS_A, 16 + lane16, hb + lquad * 16);
            bfrag bk0 = LDSA_READ(LDS_K, lane16, hb + lquad * 16);
            bfrag bk1 = LDSA_READ(LDS_K, 16 + lane16, hb + lquad * 16);
            f32x4 sc[2][2] = {};
            sc[0][0] = MFMA(aq0, bk0, sc[0][0]);
            sc[0][1] = MFMA(aq0, bk1, sc[0][1]);
            sc[1][0] = MFMA(aq1, bk0, sc[1][0]);
            sc[1][1] = MFMA(aq1, bk1, sc[1][1]);

            const float scale = 0.17677669529663687f;
            float p_[2][2][4];
            float mx[2][4], sm[2][4];
#pragma unroll
            for (int mt = 0; mt < 2; mt++)
#pragma unroll
                for (int r = 0; r < 4; r++) {
                    p_[mt][0][r] = sc[mt][0][r] * scale;
                    p_[mt][1][r] = sc[mt][1][r] * scale;
                    mx[mt][r] = fmaxf(p_[mt][0][r], p_[mt][1][r]);
                }
#pragma unroll
            for (int d = 1; d < 16; d <<= 1)
#pragma unroll
                for (int mt = 0; mt < 2; mt++)
#pragma unroll
                    for (int r = 0; r < 4; r++)
                        mx[mt][r] = fmaxf(mx[mt][r], __shfl_xor(mx[mt][r], d));
#pragma unroll
            for (int mt = 0; mt < 2; mt++)
#pragma unroll
                for (int r = 0; r < 4; r++) {
                    float e0 = __expf(p_[mt][0][r] - mx[mt][r]);
                    float e1 = __expf(p_[mt][1][r] - mx[mt][r]);
                    p_[mt][0][r] = e0; p_[mt][1][r] = e1;
                    sm[mt][r] = e0 + e1;
                }
#pragma unroll
            for (int d = 1; d < 16; d <<= 1)
#pragma unroll
                for (int mt = 0; mt < 2; mt++)
#pragma unroll
                    for (int r = 0; r < 4; r++)
                        sm[mt][r] += __shfl_xor(sm[mt][r], d);
#pragma unroll
            for (int mt = 0; mt < 2; mt++)
#pragma unroll
                for (int r = 0; r < 4; r++) {
                    float inv = 1.0f / sm[mt][r];
                    int row = mt * 16 + lquad * 4 + r;
                    LDS_ST16(LDS_X, row, (h * 32 + lane16) * 2, f2bf(p_[mt][0][r] * inv));
                    LDS_ST16(LDS_X, row, (h * 32 + 16 + lane16) * 2, f2bf(p_[mt][1][r] * inv));
                }

            f32x4 oacc[2][2] = {};
            bfrag ap0 = LDSA_READ(LDS_X, lane16, hb + lquad * 16);
            bfrag ap1 = LDSA_READ(LDS_X, 16 + lane16, hb + lquad * 16);
            bfrag bv0 = *(const bfrag*)(smem + LDS_VT + (h * 32 + lane16) * 112 + lquad * 16);
            bfrag bv1 = *(const bfrag*)(smem + LDS_VT + (h * 32 + 16 + lane16) * 112 + lquad * 16);
            oacc[0][0] = MFMA(ap0, bv0, oacc[0][0]);
            oacc[0][1] = MFMA(ap0, bv1, oacc[0][1]);
            oacc[1][0] = MFMA(ap1, bv0, oacc[1][0]);
            oacc[1][1] = MFMA(ap1, bv1, oacc[1][1]);
#pragma unroll
            for (int mt = 0; mt < 2; mt++)
#pragma unroll
                for (int nt = 0; nt < 2; nt++)
#pragma unroll
                    for (int r = 0; r < 4; r++)
                        LDS_ST16(LDS_A, mt * 16 + lquad * 4 + r, (h * 32 + nt * 16 + lane16) * 2,
                                 f2bf(oacc[mt][nt][r]));
        }
        __syncthreads();

        // GEMM7: out = x + o @ Wo ; maxpool
        {
            const bfrag* WOF = (const bfrag*)(WF + 61440);
            f32x4 acc[2][2];
#pragma unroll
            for (int mt = 0; mt < 2; mt++)
#pragma unroll
                for (int nt = 0; nt < 2; nt++) acc[mt][nt] = accx[mt][nt];
#pragma unroll
            for (int kt = 0; kt < 4; kt++) {
                bfrag a0 = LDSA_READ(LDS_A, lane16, kt * 64 + lquad * 16);
                bfrag a1 = LDSA_READ(LDS_A, 16 + lane16, kt * 64 + lquad * 16);
                bfrag b0 = WOF[(kt * 8 + wv * 2 + 0) * 64 + l];
                bfrag b1 = WOF[(kt * 8 + wv * 2 + 1) * 64 + l];
                acc[0][0] = MFMA(a0, b0, acc[0][0]);
                acc[0][1] = MFMA(a0, b1, acc[0][1]);
                acc[1][0] = MFMA(a1, b0, acc[1][0]);
                acc[1][1] = MFMA(a1, b1, acc[1][1]);
            }
            float mnt[2];
#pragma unroll
            for (int nt = 0; nt < 2; nt++) {
                float m = acc[0][nt][0];
#pragma unroll
                for (int r = 1; r < 4; r++) m = fmaxf(m, acc[0][nt][r]);
#pragma unroll
                for (int r = 0; r < 4; r++) m = fmaxf(m, acc[1][nt][r]);
                m = fmaxf(m, __shfl_xor(m, 16));
                m = fmaxf(m, __shfl_xor(m, 32));
                mnt[nt] = m;
            }
            if (lquad == 0) {
#pragma unroll
                for (int nt = 0; nt < 2; nt++) {
                    int d = ncol + nt * 16 + lane16;
                    outp[((size_t)b * DIM + d) * S + s] = mnt[nt];
                }
            }
        }
    }
}

extern "C" void kernel_launch(void* const* d_in, const int* in_sizes, int n_in,
                              void* d_out, int out_size, void* d_ws, size_t ws_size,
                              hipStream_t stream) {
    const float* xyz = (const float*)d_in[0];
    const float* points = (const float*)d_in[1];
    const float* Wc = (const float*)d_in[2];
    const float* bc = (const float*)d_in[3];
    const float* gamma = (const float*)d_in[4];
    const float* beta = (const float*)d_in[5];
    const float* mean = (const float*)d_in[6];
    const float* var = (const float*)d_in[7];
    const float* Wq = (const float*)d_in[8];
    const float* Wk = (const float*)d_in[9];
    const float* Wv = (const float*)d_in[10];
    const float* Wo = (const float*)d_in[11];
    const float* Wp = (const float*)d_in[12];
    const float* bp = (const float*)d_in[13];

    float* out_xyz = (float*)d_out;
    float* out_pts = out_xyz + B * 3 * S;

    char* ws = (char*)d_ws;
    float* ptsT = (float*)ws;
    size_t off = (size_t)B * N * PTROW * 4;
    float* nxyz = (float*)(ws + off); off += (size_t)B * S * 3 * 4;
    unsigned short* WF = (unsigned short*)(ws + off); off += 77824 * 2;
    float* biasv = (float*)(ws + off); off += DIM * 4;
    off = (off + 255) & ~(size_t)255;
    int* flags = (int*)(ws + off);           // flags[b*16] one 64B line per batch
    int* tdone = flags + 8 * 16;             // own line

    hipMemsetAsync(flags, 0, 1024, stream);
    k_fused<<<8 + NWORK, 256, 0, stream>>>(
        xyz, points, Wc, bc, gamma, beta, mean, var, Wp, bp, Wq, Wk, Wv, Wo,
        ptsT, nxyz, out_xyz, WF, biasv, flags, tdone, out_pts);
}